// Round 6
// baseline (212.224 us; speedup 1.0000x reference)
//
#include <hip/hip_runtime.h>
#include <hip/hip_bf16.h>
#include <stdint.h>

#define Bsz 4096
#define Csz 1024

typedef __attribute__((ext_vector_type(8))) short short8;
typedef __attribute__((ext_vector_type(4))) float f32x4;

// order-preserving f32 -> u32 encoding (monotone for all non-NaN)
__device__ __forceinline__ unsigned fenc(float v) {
  unsigned u = __float_as_uint(v);
  return (u & 0x80000000u) ? ~u : (u | 0x80000000u);
}

__device__ __forceinline__ uint32_t rotl32(uint32_t x, int r) {
  return (x << r) | (x >> (32 - r));
}

// ---------------- K1: row stats + bf16 cast + fused threefry rand_idx -------
// Blocks 0..4095: per-row max/sumexp/sq/CE + bf16 cast + hard[row]=0.
// Blocks 0..2047 additionally compute rand_idx for rows (row, row+2048)
// (one threefry2x32-20 hash yields both rows' gumbel bits).
__global__ __launch_bounds__(256) void k_rowstats(
    const float* __restrict__ outs, const int* __restrict__ label,
    unsigned short* __restrict__ xb, float* __restrict__ sq,
    float* __restrict__ ce, unsigned long long* __restrict__ hard,
    int* __restrict__ ridx) {
  const int row = blockIdx.x;
  const int tid = threadIdx.x;
  const int lane = tid & 63, wid = tid >> 6;
  const float4 v = reinterpret_cast<const float4*>(outs + (size_t)row * Csz)[tid];

  ushort4 u4;
  {
    __hip_bfloat16 h;
    h = __float2bfloat16(v.x); u4.x = *reinterpret_cast<const unsigned short*>(&h);
    h = __float2bfloat16(v.y); u4.y = *reinterpret_cast<const unsigned short*>(&h);
    h = __float2bfloat16(v.z); u4.z = *reinterpret_cast<const unsigned short*>(&h);
    h = __float2bfloat16(v.w); u4.w = *reinterpret_cast<const unsigned short*>(&h);
  }
  reinterpret_cast<ushort4*>(xb + (size_t)row * Csz)[tid] = u4;

  __shared__ float wred[3][4];
  float mx = fmaxf(fmaxf(v.x, v.y), fmaxf(v.z, v.w));
#pragma unroll
  for (int off = 32; off; off >>= 1) mx = fmaxf(mx, __shfl_xor(mx, off, 64));
  if (lane == 0) wred[0][wid] = mx;
  __syncthreads();
  mx = fmaxf(fmaxf(wred[0][0], wred[0][1]), fmaxf(wred[0][2], wred[0][3]));

  float se = expf(v.x - mx) + expf(v.y - mx) + expf(v.z - mx) + expf(v.w - mx);
  float s2 = v.x * v.x + v.y * v.y + v.z * v.z + v.w * v.w;
#pragma unroll
  for (int off = 32; off; off >>= 1) {
    se += __shfl_xor(se, off, 64);
    s2 += __shfl_xor(s2, off, 64);
  }
  if (lane == 0) { wred[1][wid] = se; wred[2][wid] = s2; }
  __syncthreads();
  if (tid == 0) {
    const float set = wred[1][0] + wred[1][1] + wred[1][2] + wred[1][3];
    const float sqt = wred[2][0] + wred[2][1] + wred[2][2] + wred[2][3];
    sq[row] = sqt;
    ce[row] = -(outs[(size_t)row * Csz + label[row]] - mx - logf(set));
    hard[row] = 0ull;  // fused memset
  }

  if (row >= 2048) return;

  // ---- fused k_rand: rows row and row+2048 ----
  const int i = row;
  const int li0 = label[i], li1 = label[i + 2048];
  const uint32_t k1c = 42u, k2c = 0x1BD11BDAu ^ 42u;
  unsigned long long b0 = 0ull, b1 = 0ull;
  for (int j = tid; j < Bsz; j += 256) {
    uint32_t x0 = (uint32_t)(i * Bsz + j);
    uint32_t x1 = x0 + 8388608u;
    x1 += k1c;
#define RND(rt) { x0 += x1; x1 = rotl32(x1, rt); x1 ^= x0; }
    RND(13) RND(15) RND(26) RND(6)
    x0 += k1c; x1 += k2c + 1u;
    RND(17) RND(29) RND(16) RND(24)
    x0 += k2c; x1 += 2u;
    RND(13) RND(15) RND(26) RND(6)
    x1 += k1c + 3u;
    RND(17) RND(29) RND(16) RND(24)
    x0 += k1c; x1 += k2c + 4u;
    RND(13) RND(15) RND(26) RND(6)
    x0 += k2c; x1 += 5u;
#undef RND
    const int lj = label[j];
    if (lj != li0) {
      unsigned long long p = (((unsigned long long)(x0 >> 9)) << 32) | (uint32_t)(~j);
      if (p > b0) b0 = p;
    }
    if (lj != li1) {
      unsigned long long p = (((unsigned long long)(x1 >> 9)) << 32) | (uint32_t)(~j);
      if (p > b1) b1 = p;
    }
  }
#pragma unroll
  for (int off = 32; off; off >>= 1) {
    unsigned long long o0 = __shfl_xor(b0, off, 64); if (o0 > b0) b0 = o0;
    unsigned long long o1 = __shfl_xor(b1, off, 64); if (o1 > b1) b1 = o1;
  }
  __shared__ unsigned long long r0[4], r1[4];
  if (lane == 0) { r0[wid] = b0; r1[wid] = b1; }
  __syncthreads();
  if (tid == 0) {
#pragma unroll
    for (int w = 1; w < 4; ++w) {
      if (r0[w] > b0) b0 = r0[w];
      if (r1[w] > b1) b1 = r1[w];
    }
    ridx[i] = (int)(~(uint32_t)b0);
    ridx[i + 2048] = (int)(~(uint32_t)b1);
  }
}

// ---------------- K2: wave-independent bf16 MFMA X·X^T, tri 64x64/wave ------
// NO LDS, NO barriers. Each wave owns one triangular 64x64 tile (2080 tiles,
// 520 blocks x 4 waves). Operand fragments load global->register directly:
// lanes fr=0..15 pick 16 rows, fq=0..3 read consecutive 16B of a 64B line
// (100% line utilization; A-panel shared by the block's 4 waves -> L1/L2 hit,
// X is 8MB -> L3 resident). Register double-buffer at half-K (32 elem)
// granularity: load h+1 while MFMAing h; compiler emits counted vmcnt.
// XCD-chunked swizzle (520 = 8*65, bijective) for panel L2 locality.
__global__ __launch_bounds__(256) void k_hard(
    const unsigned short* __restrict__ xb, const float* __restrict__ sq,
    const int* __restrict__ label, unsigned long long* __restrict__ hard) {
  const int bid = (int)blockIdx.x;
  const int swz = (bid & 7) * 65 + (bid >> 3);       // XCD swizzle, 520 blocks
  const int gw = swz * 4 + (int)(threadIdx.x >> 6);  // global wave id, 0..2079
  // triangular decode: gw -> (bi, bj), bi <= bj, 64x64 tile grid
  int rem = gw, bi = 0;
  while (rem >= 64 - bi) { rem -= 64 - bi; ++bi; }
  const int bj = bi + rem;

  const int lane = (int)(threadIdx.x & 63);
  const int fr = lane & 15;   // fragment row/col index
  const int fq = lane >> 4;   // k-quad / reg-quad index

  const unsigned short* Arow = xb + (size_t)(bi * 64 + fr) * Csz;
  const unsigned short* Brow = xb + (size_t)(bj * 64 + fr) * Csz;

  f32x4 acc[4][4];
#pragma unroll
  for (int m = 0; m < 4; ++m)
#pragma unroll
    for (int n = 0; n < 4; ++n) acc[m][n] = (f32x4){0.f, 0.f, 0.f, 0.f};

  short8 aC[4], bC[4], aN[4], bN[4];

#define LOADH(A8, B8, hh) {                                              \
    const int ko = (hh) * 32 + fq * 8;                                   \
    _Pragma("unroll")                                                    \
    for (int m = 0; m < 4; ++m)                                          \
      A8[m] = *reinterpret_cast<const short8*>(Arow + m * 16 * Csz + ko);\
    _Pragma("unroll")                                                    \
    for (int n = 0; n < 4; ++n)                                          \
      B8[n] = *reinterpret_cast<const short8*>(Brow + n * 16 * Csz + ko);\
  }
#define MFMAH(A8, B8)                                                    \
  _Pragma("unroll")                                                      \
  for (int m = 0; m < 4; ++m)                                            \
    _Pragma("unroll")                                                    \
    for (int n = 0; n < 4; ++n)                                          \
      acc[m][n] = __builtin_amdgcn_mfma_f32_16x16x32_bf16(A8[m], B8[n], acc[m][n], 0, 0, 0);

  LOADH(aC, bC, 0);
#pragma unroll 1
  for (int h = 0; h < 32; h += 2) {
    LOADH(aN, bN, h + 1);          // in flight during aC/bC MFMAs
    MFMAH(aC, bC);
    if (h < 30) LOADH(aC, bC, h + 2);  // in flight during aN/bN MFMAs
    MFMAH(aN, bN);
  }
#undef LOADH
#undef MFMAH

  const float cst = -2.0f * 1024.0f * 3.1622776601683794e-8f;  // -2*c*sqrt(1e-15)

  // row-side epilogue: C/D layout col=lane&15, row=fq*4+r
#pragma unroll
  for (int m = 0; m < 4; ++m) {
#pragma unroll
    for (int r = 0; r < 4; ++r) {
      const int i = bi * 64 + m * 16 + fq * 4 + r;
      const int li = label[i];
      const float sqi = sq[i];
      float bestv = -3.0e38f;
      int bestj = 0x7FFFFFFF;
#pragma unroll
      for (int n = 0; n < 4; ++n) {
        const int j = bj * 64 + n * 16 + fr;
        const float val = sqi + sq[j] - 2.0f * acc[m][n][r] + cst;
        if (label[j] != li && val > bestv) { bestv = val; bestj = j; }
      }
      unsigned long long pack =
          (bestj == 0x7FFFFFFF)
              ? 0ull
              : (((unsigned long long)fenc(bestv)) << 32) | (unsigned)(~bestj);
#pragma unroll
      for (int off = 1; off < 16; off <<= 1) {
        unsigned long long o = __shfl_xor(pack, off, 64);
        if (o > pack) pack = o;
      }
      if (fr == 0 && pack) atomicMax(&hard[i], pack);
    }
  }

  // column-side epilogue (transpose) — all tiles; diagonal dups are identical
#pragma unroll
  for (int n = 0; n < 4; ++n) {
    const int j = bj * 64 + n * 16 + fr;
    const int lj = label[j];
    const float sqj = sq[j];
    unsigned long long pack = 0ull;
#pragma unroll
    for (int m = 0; m < 4; ++m) {
#pragma unroll
      for (int r = 0; r < 4; ++r) {
        const int i = bi * 64 + m * 16 + fq * 4 + r;
        if (label[i] != lj) {
          const float val = sq[i] + sqj - 2.0f * acc[m][n][r] + cst;
          const unsigned long long p =
              (((unsigned long long)fenc(val)) << 32) | (unsigned)(~i);
          if (p > pack) pack = p;
        }
      }
    }
    unsigned long long o;
    o = __shfl_xor(pack, 16, 64); if (o > pack) pack = o;
    o = __shfl_xor(pack, 32, 64); if (o > pack) pack = o;
    if (fq == 0 && pack) atomicMax(&hard[j], pack);
  }
}

// ---------------- K4: InfoNCE per-row term (3 f32 dots + log_softmax) --------
__global__ __launch_bounds__(256) void k_nce(
    const float* __restrict__ outs, const float* __restrict__ centers,
    const int* __restrict__ label, const unsigned long long* __restrict__ hard,
    const int* __restrict__ ridx, float* __restrict__ nce) {
  const int i = blockIdx.x;
  const int tid = threadIdx.x;
  const int lane = tid & 63, wid = tid >> 6;
  const int li = label[i];
  const int jh = (int)(~(uint32_t)hard[i]);
  const int jr = ridx[i];
  const float4 a  = reinterpret_cast<const float4*>(outs + (size_t)i * Csz)[tid];
  const float4 c  = reinterpret_cast<const float4*>(centers + (size_t)li * Csz)[tid];
  const float4 rr = reinterpret_cast<const float4*>(outs + (size_t)jr * Csz)[tid];
  const float4 hh = reinterpret_cast<const float4*>(outs + (size_t)jh * Csz)[tid];
  float dp = a.x * c.x + a.y * c.y + a.z * c.z + a.w * c.w;
  float dr = a.x * rr.x + a.y * rr.y + a.z * rr.z + a.w * rr.w;
  float dh = a.x * hh.x + a.y * hh.y + a.z * hh.z + a.w * hh.w;
#pragma unroll
  for (int off = 32; off; off >>= 1) {
    dp += __shfl_xor(dp, off, 64);
    dr += __shfl_xor(dr, off, 64);
    dh += __shfl_xor(dh, off, 64);
  }
  __shared__ float w0[4], w1[4], w2[4];
  if (lane == 0) { w0[wid] = dp; w1[wid] = dr; w2[wid] = dh; }
  __syncthreads();
  if (tid == 0) {
    const float l0 = w0[0] + w0[1] + w0[2] + w0[3];
    const float l1 = w1[0] + w1[1] + w1[2] + w1[3];
    const float l2 = w2[0] + w2[1] + w2[2] + w2[3];
    const float m = fmaxf(l0, fmaxf(l1, l2));
    const float lse = logf(expf(l0 - m) + expf(l1 - m) + expf(l2 - m));
    nce[i] = -(l0 - m - lse);
  }
}

// ---------------- K5: deterministic final reduction --------------------------
__global__ __launch_bounds__(1024) void k_final(
    const float* __restrict__ ce, const float* __restrict__ nce,
    float* __restrict__ out) {
  __shared__ double s[1024];
  const int tid = threadIdx.x;
  double v = 0.0;
#pragma unroll
  for (int q = 0; q < 4; ++q) {
    v += (double)ce[tid + q * 1024];
    v += 0.1 * (double)nce[tid + q * 1024];
  }
  s[tid] = v;
  __syncthreads();
  for (int off = 512; off; off >>= 1) {
    if (tid < off) s[tid] += s[tid + off];
    __syncthreads();
  }
  if (tid == 0) out[0] = (float)(s[0] / 4096.0);
}

extern "C" void kernel_launch(void* const* d_in, const int* in_sizes, int n_in,
                              void* d_out, int out_size, void* d_ws, size_t ws_size,
                              hipStream_t stream) {
  const float* outs = (const float*)d_in[0];
  const float* centers = (const float*)d_in[1];
  const int* label = (const int*)d_in[2];
  float* out = (float*)d_out;

  char* ws = (char*)d_ws;
  unsigned short* xb = (unsigned short*)ws;                            // 8 MB bf16 X
  unsigned long long* hard = (unsigned long long*)(ws + (8u << 20));   // 32 KB
  float* sq = (float*)(ws + (8u << 20) + 32768);                       // 16 KB
  float* ce = sq + Bsz;                                                // 16 KB
  float* nce = ce + Bsz;                                               // 16 KB
  int* ridx = (int*)(nce + Bsz);                                       // 16 KB

  k_rowstats<<<Bsz, 256, 0, stream>>>(outs, label, xb, sq, ce, hard, ridx);
  k_hard<<<520, 256, 0, stream>>>(xb, sq, label, hard);
  k_nce<<<Bsz, 256, 0, stream>>>(outs, centers, label, hard, ridx, nce);
  k_final<<<1, 1024, 0, stream>>>(ce, nce, out);
}

// Round 7
// 157.717 us; speedup vs baseline: 1.3456x; 1.3456x over previous
//
#include <hip/hip_runtime.h>
#include <hip/hip_bf16.h>
#include <stdint.h>

#define Bsz 4096
#define Csz 1024

typedef __attribute__((ext_vector_type(8))) short short8;
typedef __attribute__((ext_vector_type(4))) float f32x4;

// order-preserving f32 -> u32 encoding (monotone for all non-NaN)
__device__ __forceinline__ unsigned fenc(float v) {
  unsigned u = __float_as_uint(v);
  return (u & 0x80000000u) ? ~u : (u | 0x80000000u);
}

__device__ __forceinline__ void load_lds16(const void* g, void* l) {
  __builtin_amdgcn_global_load_lds(
      (const __attribute__((address_space(1))) void*)g,
      (__attribute__((address_space(3))) void*)l, 16, 0, 0);
}

__device__ __forceinline__ uint32_t rotl32(uint32_t x, int r) {
  return (x << r) | (x >> (32 - r));
}

// ---------------- K1: row stats + bf16 cast + fused threefry rand_idx -------
__global__ __launch_bounds__(256) void k_rowstats(
    const float* __restrict__ outs, const int* __restrict__ label,
    unsigned short* __restrict__ xb, float* __restrict__ sq,
    float* __restrict__ ce, unsigned long long* __restrict__ hard,
    int* __restrict__ ridx) {
  const int row = blockIdx.x;
  const int tid = threadIdx.x;
  const int lane = tid & 63, wid = tid >> 6;
  const float4 v = reinterpret_cast<const float4*>(outs + (size_t)row * Csz)[tid];

  ushort4 u4;
  {
    __hip_bfloat16 h;
    h = __float2bfloat16(v.x); u4.x = *reinterpret_cast<const unsigned short*>(&h);
    h = __float2bfloat16(v.y); u4.y = *reinterpret_cast<const unsigned short*>(&h);
    h = __float2bfloat16(v.z); u4.z = *reinterpret_cast<const unsigned short*>(&h);
    h = __float2bfloat16(v.w); u4.w = *reinterpret_cast<const unsigned short*>(&h);
  }
  reinterpret_cast<ushort4*>(xb + (size_t)row * Csz)[tid] = u4;

  __shared__ float wred[3][4];
  float mx = fmaxf(fmaxf(v.x, v.y), fmaxf(v.z, v.w));
#pragma unroll
  for (int off = 32; off; off >>= 1) mx = fmaxf(mx, __shfl_xor(mx, off, 64));
  if (lane == 0) wred[0][wid] = mx;
  __syncthreads();
  mx = fmaxf(fmaxf(wred[0][0], wred[0][1]), fmaxf(wred[0][2], wred[0][3]));

  float se = expf(v.x - mx) + expf(v.y - mx) + expf(v.z - mx) + expf(v.w - mx);
  float s2 = v.x * v.x + v.y * v.y + v.z * v.z + v.w * v.w;
#pragma unroll
  for (int off = 32; off; off >>= 1) {
    se += __shfl_xor(se, off, 64);
    s2 += __shfl_xor(s2, off, 64);
  }
  if (lane == 0) { wred[1][wid] = se; wred[2][wid] = s2; }
  __syncthreads();
  if (tid == 0) {
    const float set = wred[1][0] + wred[1][1] + wred[1][2] + wred[1][3];
    const float sqt = wred[2][0] + wred[2][1] + wred[2][2] + wred[2][3];
    sq[row] = sqt;
    ce[row] = -(outs[(size_t)row * Csz + label[row]] - mx - logf(set));
    hard[row] = 0ull;  // fused memset
  }

  if (row >= 2048) return;

  // ---- fused k_rand: rows row and row+2048 ----
  const int i = row;
  const int li0 = label[i], li1 = label[i + 2048];
  const uint32_t k1c = 42u, k2c = 0x1BD11BDAu ^ 42u;
  unsigned long long b0 = 0ull, b1 = 0ull;
  for (int j = tid; j < Bsz; j += 256) {
    uint32_t x0 = (uint32_t)(i * Bsz + j);
    uint32_t x1 = x0 + 8388608u;
    x1 += k1c;
#define RND(rt) { x0 += x1; x1 = rotl32(x1, rt); x1 ^= x0; }
    RND(13) RND(15) RND(26) RND(6)
    x0 += k1c; x1 += k2c + 1u;
    RND(17) RND(29) RND(16) RND(24)
    x0 += k2c; x1 += 2u;
    RND(13) RND(15) RND(26) RND(6)
    x1 += k1c + 3u;
    RND(17) RND(29) RND(16) RND(24)
    x0 += k1c; x1 += k2c + 4u;
    RND(13) RND(15) RND(26) RND(6)
    x0 += k2c; x1 += 5u;
#undef RND
    const int lj = label[j];
    if (lj != li0) {
      unsigned long long p = (((unsigned long long)(x0 >> 9)) << 32) | (uint32_t)(~j);
      if (p > b0) b0 = p;
    }
    if (lj != li1) {
      unsigned long long p = (((unsigned long long)(x1 >> 9)) << 32) | (uint32_t)(~j);
      if (p > b1) b1 = p;
    }
  }
#pragma unroll
  for (int off = 32; off; off >>= 1) {
    unsigned long long o0 = __shfl_xor(b0, off, 64); if (o0 > b0) b0 = o0;
    unsigned long long o1 = __shfl_xor(b1, off, 64); if (o1 > b1) b1 = o1;
  }
  __shared__ unsigned long long r0[4], r1[4];
  if (lane == 0) { r0[wid] = b0; r1[wid] = b1; }
  __syncthreads();
  if (tid == 0) {
#pragma unroll
    for (int w = 1; w < 4; ++w) {
      if (r0[w] > b0) b0 = r0[w];
      if (r1[w] > b1) b1 = r1[w];
    }
    ridx[i] = (int)(~(uint32_t)b0);
    ridx[i + 2048] = (int)(~(uint32_t)b1);
  }
}

// ---------------- K2: bf16 MFMA X·X^T, 256x256 tiles, 8 waves ---------------
// Full 16x16 tile grid = 256 blocks (1/CU). 8 waves (512 thr) in 2M x 4N;
// per-wave output 128x64 = 8x4 frags of 16x16; BK=64, 16 K-tiles.
// LDS 128KB: A,B tiles [256][64] double-buffered. Counted vmcnt(8) (never 0
// mid-loop); lgkmcnt(0)+barrier as WAR fence before re-staging (r5-proven).
// XOR swizzle: chunk_stored = chunk_logical ^ (row&7), via pre-swizzled
// global source (gload_lds dest stays linear, rule #21) + XOR'd read addrs.
// XCD swizzle: 32 consecutive blocks (2 bi-rows) per XCD for A-panel reuse.
__global__ __launch_bounds__(512, 2) void k_hard(
    const unsigned short* __restrict__ xb, const float* __restrict__ sq,
    const int* __restrict__ label, unsigned long long* __restrict__ hard) {
  __shared__ unsigned short As[2][256 * 64];
  __shared__ unsigned short Bs[2][256 * 64];

  const int bid = (int)blockIdx.x;
  const int swz = (bid & 7) * 32 + (bid >> 3);  // XCD swizzle (256 = 8*32)
  const int bi = swz >> 4, bj = swz & 15;

  const int tid = (int)threadIdx.x;
  const int wid = tid >> 6, lane = tid & 63;
  const int wm = wid >> 2;    // 0..1: wave row (128 rows each)
  const int wn = wid & 3;     // 0..3: wave col (64 cols each)
  const int fr = lane & 15;   // fragment row/col index
  const int fq = lane >> 4;   // k-quad / reg-quad index
  const int sx = lane & 7;    // read-side swizzle xor (== row&7 of lane's rows)

  f32x4 acc[8][4];
#pragma unroll
  for (int m = 0; m < 8; ++m)
#pragma unroll
    for (int n = 0; n < 4; ++n) acc[m][n] = (f32x4){0.f, 0.f, 0.f, 0.f};

  const unsigned short* Ag = xb + (size_t)(bi * 256) * Csz;
  const unsigned short* Bg = xb + (size_t)(bj * 256) * Csz;
  const int lrow = lane >> 3;                 // row within 8-row staging call
  const int lch = ((lane & 7) ^ lrow) * 8;    // pre-swizzled source chunk

  auto STAGE = [&](int buf, int kt) {         // 8 loads/wave (vmcnt +8)
#pragma unroll
    for (int c = 0; c < 4; ++c) {
      const int r = wid * 32 + c * 8;         // covers 256 rows across 8 waves
      load_lds16(Ag + (size_t)(r + lrow) * Csz + kt + lch, &As[buf][r * 64]);
      load_lds16(Bg + (size_t)(r + lrow) * Csz + kt + lch, &Bs[buf][r * 64]);
    }
  };
  auto COMPUTE = [&](int buf) {
#pragma unroll
    for (int kh = 0; kh < 2; ++kh) {
      const int choff = ((kh * 4 + fq) ^ sx) * 8;  // swizzled element offset
      short8 a[8], b[4];
#pragma unroll
      for (int m = 0; m < 8; ++m)
        a[m] = *reinterpret_cast<const short8*>(
            &As[buf][(wm * 128 + m * 16 + fr) * 64 + choff]);
#pragma unroll
      for (int n = 0; n < 4; ++n)
        b[n] = *reinterpret_cast<const short8*>(
            &Bs[buf][(wn * 64 + n * 16 + fr) * 64 + choff]);
      __builtin_amdgcn_s_setprio(1);
#pragma unroll
      for (int m = 0; m < 8; ++m)
#pragma unroll
        for (int n = 0; n < 4; ++n)
          acc[m][n] = __builtin_amdgcn_mfma_f32_16x16x32_bf16(a[m], b[n], acc[m][n], 0, 0, 0);
      __builtin_amdgcn_s_setprio(0);
    }
  };

  STAGE(0, 0);
  STAGE(1, 64);
#pragma unroll 1
  for (int t = 0; t < 14; ++t) {
    asm volatile("s_waitcnt vmcnt(8)" ::: "memory");  // tile t landed (t+1 in flight)
    __builtin_amdgcn_s_barrier();
    COMPUTE(t & 1);
    asm volatile("s_waitcnt lgkmcnt(0)" ::: "memory");  // this wave's LDS reads done
    __builtin_amdgcn_sched_barrier(0);
    __builtin_amdgcn_s_barrier();                       // all waves done -> WAR safe
    STAGE(t & 1, (t + 2) * 64);                         // restage consumed buffer
  }
  asm volatile("s_waitcnt vmcnt(8)" ::: "memory");  // tile 14 landed
  __builtin_amdgcn_s_barrier();
  COMPUTE(0);
  asm volatile("s_waitcnt vmcnt(0)" ::: "memory");  // tile 15 landed
  __builtin_amdgcn_s_barrier();
  COMPUTE(1);

  const float cst = -2.0f * 1024.0f * 3.1622776601683794e-8f;  // -2*c*sqrt(1e-15)

  // epilogue: C/D layout col(B-side)=lane&15, row(A-side)=fq*4+reg
#pragma unroll
  for (int m = 0; m < 8; ++m) {
#pragma unroll
    for (int r = 0; r < 4; ++r) {
      const int i = bi * 256 + wm * 128 + m * 16 + fq * 4 + r;
      const int li = label[i];
      const float sqi = sq[i];
      float bestv = -3.0e38f;
      int bestj = 0x7FFFFFFF;
#pragma unroll
      for (int n = 0; n < 4; ++n) {
        const int j = bj * 256 + wn * 64 + n * 16 + fr;
        const float val = sqi + sq[j] - 2.0f * acc[m][n][r] + cst;
        if (label[j] != li && val > bestv) { bestv = val; bestj = j; }
      }
      unsigned long long pack =
          (bestj == 0x7FFFFFFF)
              ? 0ull
              : (((unsigned long long)fenc(bestv)) << 32) | (unsigned)(~bestj);
#pragma unroll
      for (int off = 1; off < 16; off <<= 1) {
        unsigned long long o = __shfl_xor(pack, off, 64);
        if (o > pack) pack = o;
      }
      if (fr == 0 && pack) atomicMax(&hard[i], pack);
    }
  }
}

// ---------------- K4: InfoNCE per-row term (3 f32 dots + log_softmax) --------
__global__ __launch_bounds__(256) void k_nce(
    const float* __restrict__ outs, const float* __restrict__ centers,
    const int* __restrict__ label, const unsigned long long* __restrict__ hard,
    const int* __restrict__ ridx, float* __restrict__ nce) {
  const int i = blockIdx.x;
  const int tid = threadIdx.x;
  const int lane = tid & 63, wid = tid >> 6;
  const int li = label[i];
  const int jh = (int)(~(uint32_t)hard[i]);
  const int jr = ridx[i];
  const float4 a  = reinterpret_cast<const float4*>(outs + (size_t)i * Csz)[tid];
  const float4 c  = reinterpret_cast<const float4*>(centers + (size_t)li * Csz)[tid];
  const float4 rr = reinterpret_cast<const float4*>(outs + (size_t)jr * Csz)[tid];
  const float4 hh = reinterpret_cast<const float4*>(outs + (size_t)jh * Csz)[tid];
  float dp = a.x * c.x + a.y * c.y + a.z * c.z + a.w * c.w;
  float dr = a.x * rr.x + a.y * rr.y + a.z * rr.z + a.w * rr.w;
  float dh = a.x * hh.x + a.y * hh.y + a.z * hh.z + a.w * hh.w;
#pragma unroll
  for (int off = 32; off; off >>= 1) {
    dp += __shfl_xor(dp, off, 64);
    dr += __shfl_xor(dr, off, 64);
    dh += __shfl_xor(dh, off, 64);
  }
  __shared__ float w0[4], w1[4], w2[4];
  if (lane == 0) { w0[wid] = dp; w1[wid] = dr; w2[wid] = dh; }
  __syncthreads();
  if (tid == 0) {
    const float l0 = w0[0] + w0[1] + w0[2] + w0[3];
    const float l1 = w1[0] + w1[1] + w1[2] + w1[3];
    const float l2 = w2[0] + w2[1] + w2[2] + w2[3];
    const float m = fmaxf(l0, fmaxf(l1, l2));
    const float lse = logf(expf(l0 - m) + expf(l1 - m) + expf(l2 - m));
    nce[i] = -(l0 - m - lse);
  }
}

// ---------------- K5: deterministic final reduction --------------------------
__global__ __launch_bounds__(1024) void k_final(
    const float* __restrict__ ce, const float* __restrict__ nce,
    float* __restrict__ out) {
  __shared__ double s[1024];
  const int tid = threadIdx.x;
  double v = 0.0;
#pragma unroll
  for (int q = 0; q < 4; ++q) {
    v += (double)ce[tid + q * 1024];
    v += 0.1 * (double)nce[tid + q * 1024];
  }
  s[tid] = v;
  __syncthreads();
  for (int off = 512; off; off >>= 1) {
    if (tid < off) s[tid] += s[tid + off];
    __syncthreads();
  }
  if (tid == 0) out[0] = (float)(s[0] / 4096.0);
}

extern "C" void kernel_launch(void* const* d_in, const int* in_sizes, int n_in,
                              void* d_out, int out_size, void* d_ws, size_t ws_size,
                              hipStream_t stream) {
  const float* outs = (const float*)d_in[0];
  const float* centers = (const float*)d_in[1];
  const int* label = (const int*)d_in[2];
  float* out = (float*)d_out;

  char* ws = (char*)d_ws;
  unsigned short* xb = (unsigned short*)ws;                            // 8 MB bf16 X
  unsigned long long* hard = (unsigned long long*)(ws + (8u << 20));   // 32 KB
  float* sq = (float*)(ws + (8u << 20) + 32768);                       // 16 KB
  float* ce = sq + Bsz;                                                // 16 KB
  float* nce = ce + Bsz;                                               // 16 KB
  int* ridx = (int*)(nce + Bsz);                                       // 16 KB

  k_rowstats<<<Bsz, 256, 0, stream>>>(outs, label, xb, sq, ce, hard, ridx);
  k_hard<<<256, 512, 0, stream>>>(xb, sq, label, hard);
  k_nce<<<Bsz, 256, 0, stream>>>(outs, centers, label, hard, ridx, nce);
  k_final<<<1, 1024, 0, stream>>>(ce, nce, out);
}